// Round 6
// baseline (511.221 us; speedup 1.0000x reference)
//
#include <hip/hip_runtime.h>
#include <hip/hip_bf16.h>
#include <stdint.h>

#define HN 16      // heads
#define TT 2048    // seq len (T == S)
#define BBATCH 2
#define EE 1024
#define HD 64
#define MM 4096    // TT*BBATCH

// Q projection is pre-scaled by 0.125*log2(e) so softmax uses raw v_exp_f32
// (exp2) with no per-element multiply: exp2(q'.k) == exp(0.125*q.k).
#define SCALEQ 0.18033688011112042f

typedef __attribute__((ext_vector_type(8))) __bf16 bfrag;
typedef __attribute__((ext_vector_type(4))) float f32x4;
typedef __attribute__((ext_vector_type(4))) short s16x4;

__device__ __forceinline__ void gll16(const void* g, void* lds) {
  __builtin_amdgcn_global_load_lds(
      (const __attribute__((address_space(1))) void*)g,
      (__attribute__((address_space(3))) void*)lds, 16, 0, 0);
}

__device__ __forceinline__ f32x4 mfma_bf16(bfrag a, bfrag b, f32x4 c) {
  return __builtin_amdgcn_mfma_f32_16x16x32_bf16(a, b, c, 0, 0, 0);
}

// ---- XOR-swizzled 64-elem-row LDS tiles (16B chunk c of row r at c^(r&7)) --
__device__ __forceinline__ const bfrag* fragp(const __bf16* base, int row, int e) {
  return (const bfrag*)(base + row * 64 + ((((e >> 3) ^ row) & 7) << 3));
}
__device__ __forceinline__ void stage8(const __bf16* grow0, int gstride,
                                       __bf16* tile, int r0, int lane) {
  const int rr = lane >> 3;
  const int cl = (lane & 7) ^ rr;
  gll16(grow0 + (size_t)(r0 + rr) * gstride + cl * 8, tile + r0 * 64);
}

// ---------------- fp32 -> bf16 conversion (7 tensors in one launch) -------
struct CvtArgs {
  const float* src[7];
  __bf16* dst[7];
  int n4[7];
};

__global__ __launch_bounds__(256) void cvt_all(CvtArgs a) {
  const int z = blockIdx.z;
  const int i = blockIdx.x * 256 + threadIdx.x;
  if (i < a.n4[z]) {
    float4 v = ((const float4*)a.src[z])[i];
    struct alignas(8) B4 { __bf16 a0, a1, a2, a3; };
    B4 o = {(__bf16)v.x, (__bf16)v.y, (__bf16)v.z, (__bf16)v.w};
    ((B4*)a.dst[z])[i] = o;
  }
}

// ---------------- GEMM: C(MMxEE) = X(MMxEE) * W(EExEE)^T + bias ----------
__device__ __forceinline__ void gemm_core(const __bf16* __restrict__ X,
                                          const __bf16* __restrict__ W,
                                          const float* __restrict__ bias,
                                          void* __restrict__ out, int mode,
                                          float scale) {
  __shared__ __bf16 As[128 * 32];
  __shared__ __bf16 Bs[128 * 32];
  const int tid = threadIdx.x;
  const int lane = tid & 63, wave = tid >> 6;
  const int wm = wave >> 1, wn = wave & 1;
  const int quad = lane >> 4, l16 = lane & 15;
  const int m0 = blockIdx.y * 128, n0 = blockIdx.x * 128;
  const int srow = lane >> 2;
  const int scol = (lane & 3) * 8;
  const int c0 = 2 * wave;

  f32x4 acc[4][4] = {};

  for (int k0 = 0; k0 < EE; k0 += 32) {
    #pragma unroll
    for (int c = 0; c < 2; ++c) {
      const int ch = c0 + c;
      gll16(X + (size_t)(m0 + ch * 16 + srow) * EE + k0 + scol, As + ch * 512);
      gll16(W + (size_t)(n0 + ch * 16 + srow) * EE + k0 + scol, Bs + ch * 512);
    }
    __syncthreads();
    bfrag a[4], b[4];
    #pragma unroll
    for (int f = 0; f < 4; ++f)
      a[f] = *(const bfrag*)(As + (wm * 64 + f * 16 + l16) * 32 + quad * 8);
    #pragma unroll
    for (int f = 0; f < 4; ++f)
      b[f] = *(const bfrag*)(Bs + (wn * 64 + f * 16 + l16) * 32 + quad * 8);
    #pragma unroll
    for (int fm = 0; fm < 4; ++fm)
      #pragma unroll
      for (int fn = 0; fn < 4; ++fn)
        acc[fm][fn] = mfma_bf16(a[fm], b[fn], acc[fm][fn]);
    __syncthreads();
  }

  float bv[4];
  #pragma unroll
  for (int fn = 0; fn < 4; ++fn) bv[fn] = bias[n0 + wn * 64 + fn * 16 + l16];

  #pragma unroll
  for (int fm = 0; fm < 4; ++fm) {
    #pragma unroll
    for (int r = 0; r < 4; ++r) {
      const int gm = m0 + wm * 64 + fm * 16 + quad * 4 + r;
      #pragma unroll
      for (int fn = 0; fn < 4; ++fn) {
        const int gn = n0 + wn * 64 + fn * 16 + l16;
        const float v = (acc[fm][fn][r] + bv[fn]) * scale;
        if (mode == 0) {
          const int t = gm >> 1, bb = gm & 1, h = gn >> 6, d = gn & 63;
          ((__bf16*)out)[(((size_t)(bb * HN + h)) * TT + t) * HD + d] = (__bf16)v;
        } else {
          const int s = gm >> 1, bb = gm & 1, h = gn >> 6, d = gn & 63;
          ((__bf16*)out)[(((size_t)(bb * HN + h)) * HD + d) * TT + s] = (__bf16)v;
        }
      }
    }
  }
}

__global__ __launch_bounds__(256) void gemm_qkv(
    const __bf16* __restrict__ xq, const __bf16* __restrict__ xk,
    const __bf16* __restrict__ xv, const __bf16* __restrict__ wq,
    const __bf16* __restrict__ wk, const __bf16* __restrict__ wv,
    const float* __restrict__ bq, const float* __restrict__ bk,
    const float* __restrict__ bv, __bf16* __restrict__ qo,
    __bf16* __restrict__ ko, __bf16* __restrict__ vo) {
  const __bf16 *X, *W;
  const float* bias;
  __bf16* out;
  int mode;
  float scale;
  if (blockIdx.z == 0)      { X = xq; W = wq; bias = bq; out = qo; mode = 0; scale = SCALEQ; }
  else if (blockIdx.z == 1) { X = xk; W = wk; bias = bk; out = ko; mode = 0; scale = 1.0f; }
  else                      { X = xv; W = wv; bias = bv; out = vo; mode = 2; scale = 1.0f; }
  gemm_core(X, W, bias, out, mode, scale);
}

// ---- output GEMM: 64x128 tile for 512 blocks ----------------------------
__global__ __launch_bounds__(256) void gemm_o64(const __bf16* __restrict__ X,
                                                const __bf16* __restrict__ W,
                                                const float* __restrict__ bias,
                                                float* __restrict__ out) {
  __shared__ __bf16 As[64 * 32];
  __shared__ __bf16 Bs[128 * 32];
  const int tid = threadIdx.x;
  const int lane = tid & 63, wave = tid >> 6;
  const int quad = lane >> 4, l16 = lane & 15;
  const int m0 = blockIdx.y * 64, n0 = blockIdx.x * 128;
  const int srow = lane >> 2, scol = (lane & 3) * 8;

  f32x4 acc[4][2] = {};

  for (int k0 = 0; k0 < EE; k0 += 32) {
    gll16(X + (size_t)(m0 + wave * 16 + srow) * EE + k0 + scol, As + wave * 512);
    #pragma unroll
    for (int c = 0; c < 2; ++c) {
      const int ch = 2 * wave + c;
      gll16(W + (size_t)(n0 + ch * 16 + srow) * EE + k0 + scol, Bs + ch * 512);
    }
    __syncthreads();
    bfrag a[4], b2[2];
    #pragma unroll
    for (int f = 0; f < 4; ++f)
      a[f] = *(const bfrag*)(As + (f * 16 + l16) * 32 + quad * 8);
    #pragma unroll
    for (int f = 0; f < 2; ++f)
      b2[f] = *(const bfrag*)(Bs + (wave * 32 + f * 16 + l16) * 32 + quad * 8);
    #pragma unroll
    for (int fm = 0; fm < 4; ++fm)
      #pragma unroll
      for (int fn = 0; fn < 2; ++fn)
        acc[fm][fn] = mfma_bf16(a[fm], b2[fn], acc[fm][fn]);
    __syncthreads();
  }

  float bv[2];
  #pragma unroll
  for (int fn = 0; fn < 2; ++fn) bv[fn] = bias[n0 + wave * 32 + fn * 16 + l16];

  #pragma unroll
  for (int fm = 0; fm < 4; ++fm)
    #pragma unroll
    for (int r = 0; r < 4; ++r) {
      const int gm = m0 + fm * 16 + quad * 4 + r;
      #pragma unroll
      for (int fn = 0; fn < 2; ++fn) {
        const int gn = n0 + wave * 32 + fn * 16 + l16;
        out[(size_t)gm * EE + gn] = acc[fm][fn][r] + bv[fn];
      }
    }
}

// ---------------- flash attention fwd: O (normalized) + linv -------------
// (unchanged from r5 except exp -> exp2, scale pre-folded into Q)
__global__ __launch_bounds__(256, 2) void attn_fwd(const __bf16* __restrict__ qb,
                                                   const __bf16* __restrict__ kb,
                                                   const __bf16* __restrict__ vtb,
                                                   __bf16* __restrict__ ob,
                                                   float* __restrict__ linv_ws) {
  union Sh {
    __bf16 kv[2][2][2][64 * 64];  // [pair][K=0/V=1][buf] 64KB
    float om[2][64 * 64];         // epilogue O-merge scratch (32KB, aliased)
  };
  __shared__ Sh sm;
  __shared__ float Lsum[2][128];
  __shared__ float LinvS[128];

  const int tid = threadIdx.x, lane = tid & 63, w = tid >> 6;
  const int p = w >> 1, tw = w & 1;
  const int quad = lane >> 4, l16 = lane & 15;

  const int bx = blockIdx.x;
  const int xcd = bx & 7, slot = bx >> 3;
  const int bhi = xcd * 4 + (slot >> 4);
  const int t0 = (slot & 15) * 128;
  const int b = bhi >> 4, h = bhi & 15;
  const size_t bh = (size_t)(b * HN + h);

  const __bf16* qbase = qb + (bh * TT + t0) * HD;
  const __bf16* kbase = kb + bh * TT * HD;
  const __bf16* vbase = vtb + bh * HD * TT;
  const int sBase = p * 1024;

  #pragma unroll
  for (int c = 0; c < 4; ++c) {
    stage8(kbase + (size_t)sBase * HD, HD, sm.kv[p][0][0], tw * 32 + c * 8, lane);
    stage8(vbase + sBase, TT, sm.kv[p][1][0], tw * 32 + c * 8, lane);
  }

  bfrag qf[4][2];
  #pragma unroll
  for (int fn = 0; fn < 4; ++fn)
    #pragma unroll
    for (int ks = 0; ks < 2; ++ks)
      qf[fn][ks] = *(const bfrag*)(qbase +
          (size_t)(tw * 64 + fn * 16 + l16) * HD + ks * 32 + quad * 8);

  f32x4 oacc[4][4] = {};   // [fm_d][fn_t] of O^T
  float lpart[4] = {};

  for (int it = 0; it < 16; ++it) {
    const int cur = it & 1;
    __syncthreads();
    if (it + 1 < 16) {
      const int s1 = sBase + (it + 1) * 64;
      #pragma unroll
      for (int c = 0; c < 4; ++c) {
        stage8(kbase + (size_t)s1 * HD, HD, sm.kv[p][0][1 - cur], tw * 32 + c * 8, lane);
        stage8(vbase + s1, TT, sm.kv[p][1][1 - cur], tw * 32 + c * 8, lane);
      }
    }

    // ---- S^T[s][t] = K.Q (scale+log2e folded into Q)
    f32x4 sacc[4][4] = {};
    #pragma unroll
    for (int ks = 0; ks < 2; ++ks) {
      bfrag kf[4];
      #pragma unroll
      for (int fm = 0; fm < 4; ++fm)
        kf[fm] = *fragp(sm.kv[p][0][cur], fm * 16 + l16, ks * 32 + quad * 8);
      #pragma unroll
      for (int fm = 0; fm < 4; ++fm)
        #pragma unroll
        for (int fn = 0; fn < 4; ++fn)
          sacc[fm][fn] = mfma_bf16(kf[fm], qf[fn][ks], sacc[fm][fn]);
    }

    // ---- exp2 in registers; pack 16-s frag pairs into x32 B-operands
    union PB { __bf16 hh[8]; bfrag v; } pb[2][4];
    #pragma unroll
    for (int fm = 0; fm < 4; ++fm)
      #pragma unroll
      for (int fn = 0; fn < 4; ++fn) {
        const float p0 = __builtin_amdgcn_exp2f(sacc[fm][fn][0]);
        const float p1 = __builtin_amdgcn_exp2f(sacc[fm][fn][1]);
        const float p2 = __builtin_amdgcn_exp2f(sacc[fm][fn][2]);
        const float p3 = __builtin_amdgcn_exp2f(sacc[fm][fn][3]);
        lpart[fn] += (p0 + p1) + (p2 + p3);
        const int hb = (fm & 1) * 4;
        pb[fm >> 1][fn].hh[hb + 0] = (__bf16)p0;
        pb[fm >> 1][fn].hh[hb + 1] = (__bf16)p1;
        pb[fm >> 1][fn].hh[hb + 2] = (__bf16)p2;
        pb[fm >> 1][fn].hh[hb + 3] = (__bf16)p3;
      }

    // ---- O^T[d][t] += V^T.P^T
    #pragma unroll
    for (int ks = 0; ks < 2; ++ks) {
      bfrag vf[4];
      #pragma unroll
      for (int fm = 0; fm < 4; ++fm) {
        const __bf16* base = sm.kv[p][1][cur] + (fm * 16 + l16) * 64;
        const int sw = l16 & 7, qh = quad >> 1, qo = (quad & 1) * 4;
        union VF { s16x4 q[2]; bfrag v; } u;
        u.q[0] = *(const s16x4*)(base + (((ks * 4 + qh) ^ sw) << 3) + qo);
        u.q[1] = *(const s16x4*)(base + (((ks * 4 + 2 + qh) ^ sw) << 3) + qo);
        vf[fm] = u.v;
      }
      #pragma unroll
      for (int fm = 0; fm < 4; ++fm)
        #pragma unroll
        for (int fn = 0; fn < 4; ++fn)
          oacc[fm][fn] = mfma_bf16(vf[fm], pb[ks][fn].v, oacc[fm][fn]);
    }
  }

  #pragma unroll
  for (int fn = 0; fn < 4; ++fn) {
    float v = lpart[fn];
    v += __shfl_xor(v, 16);
    v += __shfl_xor(v, 32);
    lpart[fn] = v;
  }
  if (quad == 0)
    #pragma unroll
    for (int fn = 0; fn < 4; ++fn)
      Lsum[p][tw * 64 + fn * 16 + l16] = lpart[fn];

  __syncthreads();

  if (p == 1) {
    #pragma unroll
    for (int fm = 0; fm < 4; ++fm)
      #pragma unroll
      for (int fn = 0; fn < 4; ++fn)
        #pragma unroll
        for (int r = 0; r < 4; ++r)
          sm.om[tw][(fm * 16 + quad * 4 + r) * 64 + fn * 16 + l16] = oacc[fm][fn][r];
  }
  if (tid < 128) {
    const float linv = 1.0f / (Lsum[0][tid] + Lsum[1][tid]);
    LinvS[tid] = linv;
    linv_ws[bh * TT + t0 + tid] = linv;
  }
  __syncthreads();

  if (p == 0) {
    float li[4];
    #pragma unroll
    for (int fn = 0; fn < 4; ++fn) li[fn] = LinvS[tw * 64 + fn * 16 + l16];
    #pragma unroll
    for (int fm = 0; fm < 4; ++fm)
      #pragma unroll
      for (int fn = 0; fn < 4; ++fn) {
        const int t = t0 + tw * 64 + fn * 16 + l16;
        struct alignas(8) B4 { __bf16 a0, a1, a2, a3; };
        B4 o;
        __bf16* op = &o.a0;
        #pragma unroll
        for (int r = 0; r < 4; ++r) {
          const float v = (oacc[fm][fn][r] +
              sm.om[tw][(fm * 16 + quad * 4 + r) * 64 + fn * 16 + l16]) * li[fn];
          op[r] = (__bf16)v;
        }
        *(B4*)(ob + ((size_t)t * BBATCH + b) * EE + h * HD + fm * 16 + quad * 4) = o;
      }
  }
}

// ---------------- avg_w: mean over heads of softmax probs ----------------
// Zero LDS/barriers; REGISTER double-buffered h-loop prefetch: loads for
// head h+1 issue at iter top (fire-and-forget), fully hidden behind iter
// h's 32 MFMA + 64 exp2. sacc split by fm-half to stay under 256 VGPRs.
__global__ __launch_bounds__(256, 2) void avg_attn(const __bf16* __restrict__ qb,
                                                   const __bf16* __restrict__ kb,
                                                   const float* __restrict__ linv_ws,
                                                   float* __restrict__ avg_out) {
  const int tid = threadIdx.x, lane = tid & 63, w = tid >> 6;
  const int wm = w >> 1, wn = w & 1;
  const int quad = lane >> 4, l16 = lane & 15;

  const int bx = blockIdx.x;
  const int xcd = bx & 7, slot = bx >> 3;
  const int bti = xcd * 4 + (slot >> 4);
  const int s0 = (slot & 15) * 128;
  const int b = bti >> 4, t0 = (bti & 15) * 128;

  const __bf16* qrow0 = qb + (((size_t)b * HN) * TT + t0 + wm * 64) * HD;
  const __bf16* krow0 = kb + (((size_t)b * HN) * TT + s0 + wn * 64) * HD;
  const float* lrow0 = linv_ws + ((size_t)b * HN) * TT + t0 + wm * 64;

  bfrag qf[2][4][2], kf[2][4][2];
  #pragma unroll
  for (int f = 0; f < 4; ++f)
    #pragma unroll
    for (int ks = 0; ks < 2; ++ks) {
      qf[0][f][ks] = *(const bfrag*)(qrow0 + (size_t)(f * 16 + l16) * HD + ks * 32 + quad * 8);
      kf[0][f][ks] = *(const bfrag*)(krow0 + (size_t)(f * 16 + l16) * HD + ks * 32 + quad * 8);
    }

  f32x4 aacc[4][4] = {};

  #pragma unroll
  for (int h = 0; h < HN; ++h) {
    const int cur = h & 1;
    if (h + 1 < HN) {
      const __bf16* qn = qrow0 + (size_t)(h + 1) * TT * HD;
      const __bf16* kn = krow0 + (size_t)(h + 1) * TT * HD;
      #pragma unroll
      for (int f = 0; f < 4; ++f)
        #pragma unroll
        for (int ks = 0; ks < 2; ++ks) {
          qf[1 - cur][f][ks] = *(const bfrag*)(qn + (size_t)(f * 16 + l16) * HD + ks * 32 + quad * 8);
          kf[1 - cur][f][ks] = *(const bfrag*)(kn + (size_t)(f * 16 + l16) * HD + ks * 32 + quad * 8);
        }
    }
    const float* lr = lrow0 + (size_t)h * TT;

    #pragma unroll
    for (int fmh = 0; fmh < 2; ++fmh) {
      const f32x4 lv0 = *(const f32x4*)(lr + (fmh * 2 + 0) * 16 + quad * 4);
      const f32x4 lv1 = *(const f32x4*)(lr + (fmh * 2 + 1) * 16 + quad * 4);
      f32x4 sacc[2][4] = {};
      #pragma unroll
      for (int ks = 0; ks < 2; ++ks)
        #pragma unroll
        for (int fm = 0; fm < 2; ++fm)
          #pragma unroll
          for (int fn = 0; fn < 4; ++fn)
            sacc[fm][fn] = mfma_bf16(qf[cur][fmh * 2 + fm][ks], kf[cur][fn][ks], sacc[fm][fn]);
      #pragma unroll
      for (int fm = 0; fm < 2; ++fm) {
        const f32x4 lv = fm ? lv1 : lv0;
        #pragma unroll
        for (int fn = 0; fn < 4; ++fn)
          #pragma unroll
          for (int r = 0; r < 4; ++r)
            aacc[fmh * 2 + fm][fn][r] += __builtin_amdgcn_exp2f(sacc[fm][fn][r]) * lv[r];
      }
    }
  }

  const float invh = 1.0f / (float)HN;
  #pragma unroll
  for (int fm = 0; fm < 4; ++fm)
    #pragma unroll
    for (int r = 0; r < 4; ++r) {
      const int t = t0 + wm * 64 + fm * 16 + quad * 4 + r;
      #pragma unroll
      for (int fn = 0; fn < 4; ++fn) {
        const int s = s0 + wn * 64 + fn * 16 + l16;
        avg_out[((size_t)b * TT + t) * TT + s] = aacc[fm][fn][r] * invh;
      }
    }
}

extern "C" void kernel_launch(void* const* d_in, const int* in_sizes, int n_in,
                              void* d_out, int out_size, void* d_ws, size_t ws_size,
                              hipStream_t stream) {
  (void)in_sizes; (void)n_in; (void)out_size; (void)ws_size;
  const float* query = (const float*)d_in[0];
  const float* key   = (const float*)d_in[1];
  const float* value = (const float*)d_in[2];
  const float* Wq = (const float*)d_in[3];
  const float* bq = (const float*)d_in[4];
  const float* Wk = (const float*)d_in[5];
  const float* bk = (const float*)d_in[6];
  const float* Wv = (const float*)d_in[7];
  const float* bv = (const float*)d_in[8];
  const float* Wo = (const float*)d_in[9];
  const float* bo = (const float*)d_in[10];

  char* ws = (char*)d_ws;
  size_t off = 0;
  auto wsalloc = [&](size_t bytes) -> void* {
    void* p = ws + off;
    off += (bytes + 255) & ~(size_t)255;
    return p;
  };
  const size_t XE = (size_t)MM * EE;
  const size_t WE = (size_t)EE * EE;
  __bf16* xq   = (__bf16*)wsalloc(XE * 2);
  __bf16* xk   = (__bf16*)wsalloc(XE * 2);
  __bf16* xv   = (__bf16*)wsalloc(XE * 2);
  __bf16* wqb  = (__bf16*)wsalloc(WE * 2);
  __bf16* wkb  = (__bf16*)wsalloc(WE * 2);
  __bf16* wvb  = (__bf16*)wsalloc(WE * 2);
  __bf16* wob  = (__bf16*)wsalloc(WE * 2);
  __bf16* qbuf = (__bf16*)wsalloc(XE * 2);
  __bf16* kbuf = (__bf16*)wsalloc(XE * 2);
  __bf16* vtbuf= (__bf16*)wsalloc(XE * 2);
  __bf16* obuf = (__bf16*)wsalloc(XE * 2);
  float* linv  = (float*)wsalloc((size_t)BBATCH * HN * TT * 4);

  CvtArgs ca;
  ca.src[0] = query; ca.dst[0] = xq;  ca.n4[0] = (int)(XE / 4);
  ca.src[1] = key;   ca.dst[1] = xk;  ca.n4[1] = (int)(XE / 4);
  ca.src[2] = value; ca.dst[2] = xv;  ca.n4[2] = (int)(XE / 4);
  ca.src[3] = Wq;    ca.dst[3] = wqb; ca.n4[3] = (int)(WE / 4);
  ca.src[4] = Wk;    ca.dst[4] = wkb; ca.n4[4] = (int)(WE / 4);
  ca.src[5] = Wv;    ca.dst[5] = wvb; ca.n4[5] = (int)(WE / 4);
  ca.src[6] = Wo;    ca.dst[6] = wob; ca.n4[6] = (int)(WE / 4);
  cvt_all<<<dim3(4096, 1, 7), 256, 0, stream>>>(ca);

  gemm_qkv<<<dim3(8, 32, 3), 256, 0, stream>>>(xq, xk, xv, wqb, wkb, wvb,
                                               bq, bk, bv, qbuf, kbuf, vtbuf);

  attn_fwd<<<dim3(512), 256, 0, stream>>>(qbuf, kbuf, vtbuf, obuf, linv);

  float* avg_out = (float*)d_out + (size_t)TT * BBATCH * EE;
  avg_attn<<<dim3(512), 256, 0, stream>>>(qbuf, kbuf, linv, avg_out);

  gemm_o64<<<dim3(8, 64), 256, 0, stream>>>(obuf, wob, bo, (float*)d_out);
}

// Round 7
// 264.710 us; speedup vs baseline: 1.9312x; 1.9312x over previous
//
#include <hip/hip_runtime.h>
#include <hip/hip_bf16.h>
#include <stdint.h>

#define HN 16      // heads
#define TT 2048    // seq len (T == S)
#define BBATCH 2
#define EE 1024
#define HD 64
#define MM 4096    // TT*BBATCH

// Q projection pre-scaled by 0.125*log2(e): exp2(q'.k) == exp(0.125*q.k).
#define SCALEQ 0.18033688011112042f

typedef __attribute__((ext_vector_type(8))) __bf16 bfrag;
typedef __attribute__((ext_vector_type(4))) float f32x4;
typedef __attribute__((ext_vector_type(4))) short s16x4;

__device__ __forceinline__ void gll16(const void* g, void* lds) {
  __builtin_amdgcn_global_load_lds(
      (const __attribute__((address_space(1))) void*)g,
      (__attribute__((address_space(3))) void*)lds, 16, 0, 0);
}

__device__ __forceinline__ f32x4 mfma_bf16(bfrag a, bfrag b, f32x4 c) {
  return __builtin_amdgcn_mfma_f32_16x16x32_bf16(a, b, c, 0, 0, 0);
}

// ---- XOR-swizzled 64-elem-row LDS tiles (16B chunk c of row r at c^(r&7)) --
__device__ __forceinline__ const bfrag* fragp(const __bf16* base, int row, int e) {
  return (const bfrag*)(base + row * 64 + ((((e >> 3) ^ row) & 7) << 3));
}
__device__ __forceinline__ void stage8(const __bf16* grow0, int gstride,
                                       __bf16* tile, int r0, int lane) {
  const int rr = lane >> 3;
  const int cl = (lane & 7) ^ rr;
  gll16(grow0 + (size_t)(r0 + rr) * gstride + cl * 8, tile + r0 * 64);
}

// ---------------- fp32 -> bf16 conversion (7 tensors in one launch) -------
struct CvtArgs {
  const float* src[7];
  __bf16* dst[7];
  int n4[7];
};

__global__ __launch_bounds__(256) void cvt_all(CvtArgs a) {
  const int z = blockIdx.z;
  const int i = blockIdx.x * 256 + threadIdx.x;
  if (i < a.n4[z]) {
    float4 v = ((const float4*)a.src[z])[i];
    struct alignas(8) B4 { __bf16 a0, a1, a2, a3; };
    B4 o = {(__bf16)v.x, (__bf16)v.y, (__bf16)v.z, (__bf16)v.w};
    ((B4*)a.dst[z])[i] = o;
  }
}

// ---------------- GEMM: C(MMxEE) = X(MMxEE) * W(EExEE)^T + bias ----------
__device__ __forceinline__ void gemm_core(const __bf16* __restrict__ X,
                                          const __bf16* __restrict__ W,
                                          const float* __restrict__ bias,
                                          void* __restrict__ out, int mode,
                                          float scale) {
  __shared__ __bf16 As[128 * 32];
  __shared__ __bf16 Bs[128 * 32];
  const int tid = threadIdx.x;
  const int lane = tid & 63, wave = tid >> 6;
  const int wm = wave >> 1, wn = wave & 1;
  const int quad = lane >> 4, l16 = lane & 15;
  const int m0 = blockIdx.y * 128, n0 = blockIdx.x * 128;
  const int srow = lane >> 2;
  const int scol = (lane & 3) * 8;
  const int c0 = 2 * wave;

  f32x4 acc[4][4] = {};

  for (int k0 = 0; k0 < EE; k0 += 32) {
    #pragma unroll
    for (int c = 0; c < 2; ++c) {
      const int ch = c0 + c;
      gll16(X + (size_t)(m0 + ch * 16 + srow) * EE + k0 + scol, As + ch * 512);
      gll16(W + (size_t)(n0 + ch * 16 + srow) * EE + k0 + scol, Bs + ch * 512);
    }
    __syncthreads();
    bfrag a[4], b[4];
    #pragma unroll
    for (int f = 0; f < 4; ++f)
      a[f] = *(const bfrag*)(As + (wm * 64 + f * 16 + l16) * 32 + quad * 8);
    #pragma unroll
    for (int f = 0; f < 4; ++f)
      b[f] = *(const bfrag*)(Bs + (wn * 64 + f * 16 + l16) * 32 + quad * 8);
    #pragma unroll
    for (int fm = 0; fm < 4; ++fm)
      #pragma unroll
      for (int fn = 0; fn < 4; ++fn)
        acc[fm][fn] = mfma_bf16(a[fm], b[fn], acc[fm][fn]);
    __syncthreads();
  }

  float bv[4];
  #pragma unroll
  for (int fn = 0; fn < 4; ++fn) bv[fn] = bias[n0 + wn * 64 + fn * 16 + l16];

  #pragma unroll
  for (int fm = 0; fm < 4; ++fm) {
    #pragma unroll
    for (int r = 0; r < 4; ++r) {
      const int gm = m0 + wm * 64 + fm * 16 + quad * 4 + r;
      #pragma unroll
      for (int fn = 0; fn < 4; ++fn) {
        const int gn = n0 + wn * 64 + fn * 16 + l16;
        const float v = (acc[fm][fn][r] + bv[fn]) * scale;
        if (mode == 0) {
          const int t = gm >> 1, bb = gm & 1, h = gn >> 6, d = gn & 63;
          ((__bf16*)out)[(((size_t)(bb * HN + h)) * TT + t) * HD + d] = (__bf16)v;
        } else {
          const int s = gm >> 1, bb = gm & 1, h = gn >> 6, d = gn & 63;
          ((__bf16*)out)[(((size_t)(bb * HN + h)) * HD + d) * TT + s] = (__bf16)v;
        }
      }
    }
  }
}

__global__ __launch_bounds__(256) void gemm_qkv(
    const __bf16* __restrict__ xq, const __bf16* __restrict__ xk,
    const __bf16* __restrict__ xv, const __bf16* __restrict__ wq,
    const __bf16* __restrict__ wk, const __bf16* __restrict__ wv,
    const float* __restrict__ bq, const float* __restrict__ bk,
    const float* __restrict__ bv, __bf16* __restrict__ qo,
    __bf16* __restrict__ ko, __bf16* __restrict__ vo) {
  const __bf16 *X, *W;
  const float* bias;
  __bf16* out;
  int mode;
  float scale;
  if (blockIdx.z == 0)      { X = xq; W = wq; bias = bq; out = qo; mode = 0; scale = SCALEQ; }
  else if (blockIdx.z == 1) { X = xk; W = wk; bias = bk; out = ko; mode = 0; scale = 1.0f; }
  else                      { X = xv; W = wv; bias = bv; out = vo; mode = 2; scale = 1.0f; }
  gemm_core(X, W, bias, out, mode, scale);
}

// ---- output GEMM: 64x128 tile for 512 blocks ----------------------------
__global__ __launch_bounds__(256) void gemm_o64(const __bf16* __restrict__ X,
                                                const __bf16* __restrict__ W,
                                                const float* __restrict__ bias,
                                                float* __restrict__ out) {
  __shared__ __bf16 As[64 * 32];
  __shared__ __bf16 Bs[128 * 32];
  const int tid = threadIdx.x;
  const int lane = tid & 63, wave = tid >> 6;
  const int quad = lane >> 4, l16 = lane & 15;
  const int m0 = blockIdx.y * 64, n0 = blockIdx.x * 128;
  const int srow = lane >> 2, scol = (lane & 3) * 8;

  f32x4 acc[4][2] = {};

  for (int k0 = 0; k0 < EE; k0 += 32) {
    gll16(X + (size_t)(m0 + wave * 16 + srow) * EE + k0 + scol, As + wave * 512);
    #pragma unroll
    for (int c = 0; c < 2; ++c) {
      const int ch = 2 * wave + c;
      gll16(W + (size_t)(n0 + ch * 16 + srow) * EE + k0 + scol, Bs + ch * 512);
    }
    __syncthreads();
    bfrag a[4], b2[2];
    #pragma unroll
    for (int f = 0; f < 4; ++f)
      a[f] = *(const bfrag*)(As + (f * 16 + l16) * 32 + quad * 8);
    #pragma unroll
    for (int f = 0; f < 2; ++f)
      b2[f] = *(const bfrag*)(Bs + (wave * 32 + f * 16 + l16) * 32 + quad * 8);
    #pragma unroll
    for (int fm = 0; fm < 4; ++fm)
      #pragma unroll
      for (int fn = 0; fn < 2; ++fn)
        acc[fm][fn] = mfma_bf16(a[fm], b2[fn], acc[fm][fn]);
    __syncthreads();
  }

  float bv[2];
  #pragma unroll
  for (int fn = 0; fn < 2; ++fn) bv[fn] = bias[n0 + wave * 32 + fn * 16 + l16];

  #pragma unroll
  for (int fm = 0; fm < 4; ++fm)
    #pragma unroll
    for (int r = 0; r < 4; ++r) {
      const int gm = m0 + fm * 16 + quad * 4 + r;
      #pragma unroll
      for (int fn = 0; fn < 2; ++fn) {
        const int gn = n0 + wave * 32 + fn * 16 + l16;
        out[(size_t)gm * EE + gn] = acc[fm][fn][r] + bv[fn];
      }
    }
}

// ---------------- flash attention fwd: O (normalized) + linv -------------
// (unchanged from r6: register-P, LDS only for K/V, exp2, XCD swizzle)
__global__ __launch_bounds__(256, 2) void attn_fwd(const __bf16* __restrict__ qb,
                                                   const __bf16* __restrict__ kb,
                                                   const __bf16* __restrict__ vtb,
                                                   __bf16* __restrict__ ob,
                                                   float* __restrict__ linv_ws) {
  union Sh {
    __bf16 kv[2][2][2][64 * 64];  // [pair][K=0/V=1][buf] 64KB
    float om[2][64 * 64];         // epilogue O-merge scratch (32KB, aliased)
  };
  __shared__ Sh sm;
  __shared__ float Lsum[2][128];
  __shared__ float LinvS[128];

  const int tid = threadIdx.x, lane = tid & 63, w = tid >> 6;
  const int p = w >> 1, tw = w & 1;
  const int quad = lane >> 4, l16 = lane & 15;

  const int bx = blockIdx.x;
  const int xcd = bx & 7, slot = bx >> 3;
  const int bhi = xcd * 4 + (slot >> 4);
  const int t0 = (slot & 15) * 128;
  const int b = bhi >> 4, h = bhi & 15;
  const size_t bh = (size_t)(b * HN + h);

  const __bf16* qbase = qb + (bh * TT + t0) * HD;
  const __bf16* kbase = kb + bh * TT * HD;
  const __bf16* vbase = vtb + bh * HD * TT;
  const int sBase = p * 1024;

  #pragma unroll
  for (int c = 0; c < 4; ++c) {
    stage8(kbase + (size_t)sBase * HD, HD, sm.kv[p][0][0], tw * 32 + c * 8, lane);
    stage8(vbase + sBase, TT, sm.kv[p][1][0], tw * 32 + c * 8, lane);
  }

  bfrag qf[4][2];
  #pragma unroll
  for (int fn = 0; fn < 4; ++fn)
    #pragma unroll
    for (int ks = 0; ks < 2; ++ks)
      qf[fn][ks] = *(const bfrag*)(qbase +
          (size_t)(tw * 64 + fn * 16 + l16) * HD + ks * 32 + quad * 8);

  f32x4 oacc[4][4] = {};   // [fm_d][fn_t] of O^T
  float lpart[4] = {};

  for (int it = 0; it < 16; ++it) {
    const int cur = it & 1;
    __syncthreads();
    if (it + 1 < 16) {
      const int s1 = sBase + (it + 1) * 64;
      #pragma unroll
      for (int c = 0; c < 4; ++c) {
        stage8(kbase + (size_t)s1 * HD, HD, sm.kv[p][0][1 - cur], tw * 32 + c * 8, lane);
        stage8(vbase + s1, TT, sm.kv[p][1][1 - cur], tw * 32 + c * 8, lane);
      }
    }

    // ---- S^T[s][t] = K.Q (scale+log2e folded into Q)
    f32x4 sacc[4][4] = {};
    #pragma unroll
    for (int ks = 0; ks < 2; ++ks) {
      bfrag kf[4];
      #pragma unroll
      for (int fm = 0; fm < 4; ++fm)
        kf[fm] = *fragp(sm.kv[p][0][cur], fm * 16 + l16, ks * 32 + quad * 8);
      #pragma unroll
      for (int fm = 0; fm < 4; ++fm)
        #pragma unroll
        for (int fn = 0; fn < 4; ++fn)
          sacc[fm][fn] = mfma_bf16(kf[fm], qf[fn][ks], sacc[fm][fn]);
    }

    // ---- exp2 in registers; pack 16-s frag pairs into x32 B-operands
    union PB { __bf16 hh[8]; bfrag v; } pb[2][4];
    #pragma unroll
    for (int fm = 0; fm < 4; ++fm)
      #pragma unroll
      for (int fn = 0; fn < 4; ++fn) {
        const float p0 = __builtin_amdgcn_exp2f(sacc[fm][fn][0]);
        const float p1 = __builtin_amdgcn_exp2f(sacc[fm][fn][1]);
        const float p2 = __builtin_amdgcn_exp2f(sacc[fm][fn][2]);
        const float p3 = __builtin_amdgcn_exp2f(sacc[fm][fn][3]);
        lpart[fn] += (p0 + p1) + (p2 + p3);
        const int hb = (fm & 1) * 4;
        pb[fm >> 1][fn].hh[hb + 0] = (__bf16)p0;
        pb[fm >> 1][fn].hh[hb + 1] = (__bf16)p1;
        pb[fm >> 1][fn].hh[hb + 2] = (__bf16)p2;
        pb[fm >> 1][fn].hh[hb + 3] = (__bf16)p3;
      }

    // ---- O^T[d][t] += V^T.P^T
    #pragma unroll
    for (int ks = 0; ks < 2; ++ks) {
      bfrag vf[4];
      #pragma unroll
      for (int fm = 0; fm < 4; ++fm) {
        const __bf16* base = sm.kv[p][1][cur] + (fm * 16 + l16) * 64;
        const int sw = l16 & 7, qh = quad >> 1, qo = (quad & 1) * 4;
        union VF { s16x4 q[2]; bfrag v; } u;
        u.q[0] = *(const s16x4*)(base + (((ks * 4 + qh) ^ sw) << 3) + qo);
        u.q[1] = *(const s16x4*)(base + (((ks * 4 + 2 + qh) ^ sw) << 3) + qo);
        vf[fm] = u.v;
      }
      #pragma unroll
      for (int fm = 0; fm < 4; ++fm)
        #pragma unroll
        for (int fn = 0; fn < 4; ++fn)
          oacc[fm][fn] = mfma_bf16(vf[fm], pb[ks][fn].v, oacc[fm][fn]);
    }
  }

  #pragma unroll
  for (int fn = 0; fn < 4; ++fn) {
    float v = lpart[fn];
    v += __shfl_xor(v, 16);
    v += __shfl_xor(v, 32);
    lpart[fn] = v;
  }
  if (quad == 0)
    #pragma unroll
    for (int fn = 0; fn < 4; ++fn)
      Lsum[p][tw * 64 + fn * 16 + l16] = lpart[fn];

  __syncthreads();

  if (p == 1) {
    #pragma unroll
    for (int fm = 0; fm < 4; ++fm)
      #pragma unroll
      for (int fn = 0; fn < 4; ++fn)
        #pragma unroll
        for (int r = 0; r < 4; ++r)
          sm.om[tw][(fm * 16 + quad * 4 + r) * 64 + fn * 16 + l16] = oacc[fm][fn][r];
  }
  if (tid < 128) {
    const float linv = 1.0f / (Lsum[0][tid] + Lsum[1][tid]);
    LinvS[tid] = linv;
    linv_ws[bh * TT + t0 + tid] = linv;
  }
  __syncthreads();

  if (p == 0) {
    float li[4];
    #pragma unroll
    for (int fn = 0; fn < 4; ++fn) li[fn] = LinvS[tw * 64 + fn * 16 + l16];
    #pragma unroll
    for (int fm = 0; fm < 4; ++fm)
      #pragma unroll
      for (int fn = 0; fn < 4; ++fn) {
        const int t = t0 + tw * 64 + fn * 16 + l16;
        struct alignas(8) B4 { __bf16 a0, a1, a2, a3; };
        B4 o;
        __bf16* op = &o.a0;
        #pragma unroll
        for (int r = 0; r < 4; ++r) {
          const float v = (oacc[fm][fn][r] +
              sm.om[tw][(fm * 16 + quad * 4 + r) * 64 + fn * 16 + l16]) * li[fn];
          op[r] = (__bf16)v;
        }
        *(B4*)(ob + ((size_t)t * BBATCH + b) * EE + h * HD + fm * 16 + quad * 4) = o;
      }
  }
}

// ---------------- avg_w: mean over heads of softmax probs ----------------
// attn_fwd's proven staging pattern: Q+K via async global_load_lds into
// XOR-swizzled LDS, double-buffered over the h-loop, ONE barrier per head.
// (r6's register dbuf spilled to scratch: 465MB WRITE_SIZE. LDS is the
// only home for a 32KB double buffer.)  64KB LDS -> 2 blocks/CU.
__global__ __launch_bounds__(256, 2) void avg_attn(const __bf16* __restrict__ qb,
                                                   const __bf16* __restrict__ kb,
                                                   const float* __restrict__ linv_ws,
                                                   float* __restrict__ avg_out) {
  __shared__ __bf16 Qs[2][128 * 64];   // 2 x 16KB
  __shared__ __bf16 Ks[2][128 * 64];   // 2 x 16KB

  const int tid = threadIdx.x, lane = tid & 63, w = tid >> 6;
  const int wm = w >> 1, wn = w & 1;
  const int quad = lane >> 4, l16 = lane & 15;

  const int bx = blockIdx.x;
  const int xcd = bx & 7, slot = bx >> 3;
  const int bti = xcd * 4 + (slot >> 4);
  const int s0 = (slot & 15) * 128;
  const int b = bti >> 4, t0 = (bti & 15) * 128;

  const __bf16* qt = qb + (((size_t)b * HN) * TT + t0) * HD;  // +h*TT*HD per head
  const __bf16* kt = kb + (((size_t)b * HN) * TT + s0) * HD;
  const float* lrow0 = linv_ws + ((size_t)b * HN) * TT + t0 + wm * 64;

  // stage head 0: each wave stages 32 rows of Q and of K
  #pragma unroll
  for (int c = 0; c < 4; ++c) {
    stage8(qt, HD, Qs[0], w * 32 + c * 8, lane);
    stage8(kt, HD, Ks[0], w * 32 + c * 8, lane);
  }

  f32x4 aacc[4][4] = {};

  for (int h = 0; h < HN; ++h) {
    const int cur = h & 1;
    __syncthreads();   // buf[cur] staged (vmcnt drained by barrier)
    if (h + 1 < HN) {  // async prefetch next head into buf[1-cur]
      const __bf16* qn = qt + (size_t)(h + 1) * TT * HD;
      const __bf16* kn = kt + (size_t)(h + 1) * TT * HD;
      #pragma unroll
      for (int c = 0; c < 4; ++c) {
        stage8(qn, HD, Qs[1 - cur], w * 32 + c * 8, lane);
        stage8(kn, HD, Ks[1 - cur], w * 32 + c * 8, lane);
      }
    }

    f32x4 sacc[4][4] = {};
    #pragma unroll
    for (int ks = 0; ks < 2; ++ks) {
      bfrag qf4[4], kf4[4];
      #pragma unroll
      for (int f = 0; f < 4; ++f)
        qf4[f] = *fragp(Qs[cur], wm * 64 + f * 16 + l16, ks * 32 + quad * 8);
      #pragma unroll
      for (int f = 0; f < 4; ++f)
        kf4[f] = *fragp(Ks[cur], wn * 64 + f * 16 + l16, ks * 32 + quad * 8);
      #pragma unroll
      for (int fm = 0; fm < 4; ++fm)
        #pragma unroll
        for (int fn = 0; fn < 4; ++fn)
          sacc[fm][fn] = mfma_bf16(qf4[fm], kf4[fn], sacc[fm][fn]);
    }

    const float* lr = lrow0 + (size_t)h * TT;
    f32x4 lvv[4];
    #pragma unroll
    for (int fm = 0; fm < 4; ++fm)
      lvv[fm] = *(const f32x4*)(lr + fm * 16 + quad * 4);

    #pragma unroll
    for (int fm = 0; fm < 4; ++fm)
      #pragma unroll
      for (int fn = 0; fn < 4; ++fn)
        #pragma unroll
        for (int r = 0; r < 4; ++r)
          aacc[fm][fn][r] += __builtin_amdgcn_exp2f(sacc[fm][fn][r]) * lvv[fm][r];
  }

  const float invh = 1.0f / (float)HN;
  #pragma unroll
  for (int fm = 0; fm < 4; ++fm)
    #pragma unroll
    for (int r = 0; r < 4; ++r) {
      const int t = t0 + wm * 64 + fm * 16 + quad * 4 + r;
      #pragma unroll
      for (int fn = 0; fn < 4; ++fn) {
        const int s = s0 + wn * 64 + fn * 16 + l16;
        avg_out[((size_t)b * TT + t) * TT + s] = aacc[fm][fn][r] * invh;
      }
    }
}

extern "C" void kernel_launch(void* const* d_in, const int* in_sizes, int n_in,
                              void* d_out, int out_size, void* d_ws, size_t ws_size,
                              hipStream_t stream) {
  (void)in_sizes; (void)n_in; (void)out_size; (void)ws_size;
  const float* query = (const float*)d_in[0];
  const float* key   = (const float*)d_in[1];
  const float* value = (const float*)d_in[2];
  const float* Wq = (const float*)d_in[3];
  const float* bq = (const float*)d_in[4];
  const float* Wk = (const float*)d_in[5];
  const float* bk = (const float*)d_in[6];
  const float* Wv = (const float*)d_in[7];
  const float* bv = (const float*)d_in[8];
  const float* Wo = (const float*)d_in[9];
  const float* bo = (const float*)d_in[10];

  char* ws = (char*)d_ws;
  size_t off = 0;
  auto wsalloc = [&](size_t bytes) -> void* {
    void* p = ws + off;
    off += (bytes + 255) & ~(size_t)255;
    return p;
  };
  const size_t XE = (size_t)MM * EE;
  const size_t WE = (size_t)EE * EE;
  __bf16* xq   = (__bf16*)wsalloc(XE * 2);
  __bf16* xk   = (__bf16*)wsalloc(XE * 2);
  __bf16* xv   = (__bf16*)wsalloc(XE * 2);
  __bf16* wqb  = (__bf16*)wsalloc(WE * 2);
  __bf16* wkb  = (__bf16*)wsalloc(WE * 2);
  __bf16* wvb  = (__bf16*)wsalloc(WE * 2);
  __bf16* wob  = (__bf16*)wsalloc(WE * 2);
  __bf16* qbuf = (__bf16*)wsalloc(XE * 2);
  __bf16* kbuf = (__bf16*)wsalloc(XE * 2);
  __bf16* vtbuf= (__bf16*)wsalloc(XE * 2);
  __bf16* obuf = (__bf16*)wsalloc(XE * 2);
  float* linv  = (float*)wsalloc((size_t)BBATCH * HN * TT * 4);

  CvtArgs ca;
  ca.src[0] = query; ca.dst[0] = xq;  ca.n4[0] = (int)(XE / 4);
  ca.src[1] = key;   ca.dst[1] = xk;  ca.n4[1] = (int)(XE / 4);
  ca.src[2] = value; ca.dst[2] = xv;  ca.n4[2] = (int)(XE / 4);
  ca.src[3] = Wq;    ca.dst[3] = wqb; ca.n4[3] = (int)(WE / 4);
  ca.src[4] = Wk;    ca.dst[4] = wkb; ca.n4[4] = (int)(WE / 4);
  ca.src[5] = Wv;    ca.dst[5] = wvb; ca.n4[5] = (int)(WE / 4);
  ca.src[6] = Wo;    ca.dst[6] = wob; ca.n4[6] = (int)(WE / 4);
  cvt_all<<<dim3(4096, 1, 7), 256, 0, stream>>>(ca);

  gemm_qkv<<<dim3(8, 32, 3), 256, 0, stream>>>(xq, xk, xv, wqb, wkb, wvb,
                                               bq, bk, bv, qbuf, kbuf, vtbuf);

  attn_fwd<<<dim3(512), 256, 0, stream>>>(qbuf, kbuf, vtbuf, obuf, linv);

  float* avg_out = (float*)d_out + (size_t)TT * BBATCH * EE;
  avg_attn<<<dim3(512), 256, 0, stream>>>(qbuf, kbuf, linv, avg_out);

  gemm_o64<<<dim3(8, 64), 256, 0, stream>>>(obuf, wob, bo, (float*)d_out);
}

// Round 8
// 247.408 us; speedup vs baseline: 2.0663x; 1.0699x over previous
//
#include <hip/hip_runtime.h>
#include <hip/hip_bf16.h>
#include <stdint.h>

#define HN 16      // heads
#define TT 2048    // seq len (T == S)
#define BBATCH 2
#define EE 1024
#define HD 64
#define MM 4096    // TT*BBATCH

// Q projection pre-scaled by 0.125*log2(e): exp2(q'.k) == exp(0.125*q.k).
#define SCALEQ 0.18033688011112042f

typedef __attribute__((ext_vector_type(8))) __bf16 bfrag;
typedef __attribute__((ext_vector_type(4))) float f32x4;
typedef __attribute__((ext_vector_type(4))) short s16x4;

__device__ __forceinline__ void gll16(const void* g, void* lds) {
  __builtin_amdgcn_global_load_lds(
      (const __attribute__((address_space(1))) void*)g,
      (__attribute__((address_space(3))) void*)lds, 16, 0, 0);
}

__device__ __forceinline__ f32x4 mfma_bf16(bfrag a, bfrag b, f32x4 c) {
  return __builtin_amdgcn_mfma_f32_16x16x32_bf16(a, b, c, 0, 0, 0);
}

// ---- XOR-swizzled 64-elem-row LDS tiles (16B chunk c of row r at c^(r&7)) --
__device__ __forceinline__ const bfrag* fragp(const __bf16* base, int row, int e) {
  return (const bfrag*)(base + row * 64 + ((((e >> 3) ^ row) & 7) << 3));
}
__device__ __forceinline__ void stage8(const __bf16* grow0, int gstride,
                                       __bf16* tile, int r0, int lane) {
  const int rr = lane >> 3;
  const int cl = (lane & 7) ^ rr;
  gll16(grow0 + (size_t)(r0 + rr) * gstride + cl * 8, tile + r0 * 64);
}

// ---------------- fp32 -> bf16 conversion (7 tensors in one launch) -------
struct CvtArgs {
  const float* src[7];
  __bf16* dst[7];
  int n4[7];
};

__global__ __launch_bounds__(256) void cvt_all(CvtArgs a) {
  const int z = blockIdx.z;
  const int i = blockIdx.x * 256 + threadIdx.x;
  if (i < a.n4[z]) {
    float4 v = ((const float4*)a.src[z])[i];
    struct alignas(8) B4 { __bf16 a0, a1, a2, a3; };
    B4 o = {(__bf16)v.x, (__bf16)v.y, (__bf16)v.z, (__bf16)v.w};
    ((B4*)a.dst[z])[i] = o;
  }
}

// ---------------- GEMM core v2: BK=64, swizzled LDS, dbuf, 1 barrier/iter --
// C(MT x 128) tile of X(MMxEE).W(EExEE)^T+bias. Waves 2x2; wave tile
// (MT/2) x 64; 16 K-iters of (MT/16)x4x2 MFMA with prefetch in flight.
// mode 0: bf16 out head-major; mode 2: bf16 V^T; mode 3: fp32 row-major.
template <int MT>
__device__ __forceinline__ void gemm2(const __bf16* __restrict__ X,
                                      const __bf16* __restrict__ W,
                                      const float* __restrict__ bias,
                                      void* __restrict__ out, int mode,
                                      float scale, int m0, int n0,
                                      __bf16* As0, __bf16* As1,
                                      __bf16* Bs0, __bf16* Bs1) {
  const int tid = threadIdx.x, lane = tid & 63, w = tid >> 6;
  const int wm = w >> 1, wn = w & 1;
  const int quad = lane >> 4, l16 = lane & 15;
  constexpr int FM = MT / 32;   // m-frags per wave

  auto stageAB = [&](int buf, int k0) {
    __bf16* A = buf ? As1 : As0;
    __bf16* B = buf ? Bs1 : Bs0;
    #pragma unroll
    for (int c = 0; c < FM; ++c)
      stage8(X + (size_t)m0 * EE + k0, EE, A, w * (MT / 4) + c * 8, lane);
    #pragma unroll
    for (int c = 0; c < 4; ++c)
      stage8(W + (size_t)n0 * EE + k0, EE, B, w * 32 + c * 8, lane);
  };

  stageAB(0, 0);

  f32x4 acc[FM][4] = {};

  for (int it = 0; it < EE / 64; ++it) {
    const int cur = it & 1;
    __syncthreads();                 // buf[cur] staged; prior reads done
    if (it + 1 < EE / 64) stageAB(1 - cur, (it + 1) * 64);

    const __bf16* A = cur ? As1 : As0;
    const __bf16* B = cur ? Bs1 : Bs0;
    #pragma unroll
    for (int ks = 0; ks < 2; ++ks) {
      bfrag a[FM], b[4];
      #pragma unroll
      for (int f = 0; f < FM; ++f)
        a[f] = *fragp(A, wm * (MT / 2) + f * 16 + l16, ks * 32 + quad * 8);
      #pragma unroll
      for (int f = 0; f < 4; ++f)
        b[f] = *fragp(B, wn * 64 + f * 16 + l16, ks * 32 + quad * 8);
      #pragma unroll
      for (int fm = 0; fm < FM; ++fm)
        #pragma unroll
        for (int fn = 0; fn < 4; ++fn)
          acc[fm][fn] = mfma_bf16(a[fm], b[fn], acc[fm][fn]);
    }
  }

  float bv[4];
  #pragma unroll
  for (int fn = 0; fn < 4; ++fn) bv[fn] = bias[n0 + wn * 64 + fn * 16 + l16];

  #pragma unroll
  for (int fm = 0; fm < FM; ++fm) {
    #pragma unroll
    for (int r = 0; r < 4; ++r) {
      const int gm = m0 + wm * (MT / 2) + fm * 16 + quad * 4 + r;
      #pragma unroll
      for (int fn = 0; fn < 4; ++fn) {
        const int gn = n0 + wn * 64 + fn * 16 + l16;
        const float v = (acc[fm][fn][r] + bv[fn]) * scale;
        if (mode == 0) {
          const int t = gm >> 1, bb = gm & 1, h = gn >> 6, d = gn & 63;
          ((__bf16*)out)[(((size_t)(bb * HN + h)) * TT + t) * HD + d] = (__bf16)v;
        } else if (mode == 2) {
          const int s = gm >> 1, bb = gm & 1, h = gn >> 6, d = gn & 63;
          ((__bf16*)out)[(((size_t)(bb * HN + h)) * HD + d) * TT + s] = (__bf16)v;
        } else {
          ((float*)out)[(size_t)gm * EE + gn] = v;
        }
      }
    }
  }
}

// flat grid 768: bx = m + 32*(n + 8*z). bx%8 == m%8 -> the 8 n-blocks
// sharing one A-tile land on one XCD (A-tiles 1MB + B 2MB fit 4MB L2).
__global__ __launch_bounds__(256, 2) void gemm_qkv(
    const __bf16* __restrict__ xq, const __bf16* __restrict__ xk,
    const __bf16* __restrict__ xv, const __bf16* __restrict__ wq,
    const __bf16* __restrict__ wk, const __bf16* __restrict__ wv,
    const float* __restrict__ bq, const float* __restrict__ bk,
    const float* __restrict__ bv, __bf16* __restrict__ qo,
    __bf16* __restrict__ ko, __bf16* __restrict__ vo) {
  __shared__ __bf16 As[2][128 * 64];   // 32KB
  __shared__ __bf16 Bs[2][128 * 64];   // 32KB
  const int bx = blockIdx.x;
  const int m = bx & 31, n = (bx >> 5) & 7, z = bx >> 8;
  const __bf16 *X, *W;
  const float* bias;
  __bf16* out;
  int mode;
  float scale;
  if (z == 0)      { X = xq; W = wq; bias = bq; out = qo; mode = 0; scale = SCALEQ; }
  else if (z == 1) { X = xk; W = wk; bias = bk; out = ko; mode = 0; scale = 1.0f; }
  else             { X = xv; W = wv; bias = bv; out = vo; mode = 2; scale = 1.0f; }
  gemm2<128>(X, W, bias, out, mode, scale, m * 128, n * 128,
             As[0], As[1], Bs[0], Bs[1]);
}

// output GEMM: MT=64, flat grid 512: bx = m + 64*n (bx%8 == m%8).
__global__ __launch_bounds__(256, 2) void gemm_o(const __bf16* __restrict__ X,
                                                 const __bf16* __restrict__ W,
                                                 const float* __restrict__ bias,
                                                 float* __restrict__ out) {
  __shared__ __bf16 As[2][64 * 64];    // 16KB
  __shared__ __bf16 Bs[2][128 * 64];   // 32KB
  const int bx = blockIdx.x;
  const int m = bx & 63, n = bx >> 6;
  gemm2<64>(X, W, bias, out, 3, 1.0f, m * 64, n * 128,
            As[0], As[1], Bs[0], Bs[1]);
}

// ---------------- flash attention fwd: O (normalized) + linv -------------
// (unchanged from r7: register-P, LDS only for K/V, exp2, XCD swizzle)
__global__ __launch_bounds__(256, 2) void attn_fwd(const __bf16* __restrict__ qb,
                                                   const __bf16* __restrict__ kb,
                                                   const __bf16* __restrict__ vtb,
                                                   __bf16* __restrict__ ob,
                                                   float* __restrict__ linv_ws) {
  union Sh {
    __bf16 kv[2][2][2][64 * 64];  // [pair][K=0/V=1][buf] 64KB
    float om[2][64 * 64];         // epilogue O-merge scratch (32KB, aliased)
  };
  __shared__ Sh sm;
  __shared__ float Lsum[2][128];
  __shared__ float LinvS[128];

  const int tid = threadIdx.x, lane = tid & 63, w = tid >> 6;
  const int p = w >> 1, tw = w & 1;
  const int quad = lane >> 4, l16 = lane & 15;

  const int bx = blockIdx.x;
  const int xcd = bx & 7, slot = bx >> 3;
  const int bhi = xcd * 4 + (slot >> 4);
  const int t0 = (slot & 15) * 128;
  const int b = bhi >> 4, h = bhi & 15;
  const size_t bh = (size_t)(b * HN + h);

  const __bf16* qbase = qb + (bh * TT + t0) * HD;
  const __bf16* kbase = kb + bh * TT * HD;
  const __bf16* vbase = vtb + bh * HD * TT;
  const int sBase = p * 1024;

  #pragma unroll
  for (int c = 0; c < 4; ++c) {
    stage8(kbase + (size_t)sBase * HD, HD, sm.kv[p][0][0], tw * 32 + c * 8, lane);
    stage8(vbase + sBase, TT, sm.kv[p][1][0], tw * 32 + c * 8, lane);
  }

  bfrag qf[4][2];
  #pragma unroll
  for (int fn = 0; fn < 4; ++fn)
    #pragma unroll
    for (int ks = 0; ks < 2; ++ks)
      qf[fn][ks] = *(const bfrag*)(qbase +
          (size_t)(tw * 64 + fn * 16 + l16) * HD + ks * 32 + quad * 8);

  f32x4 oacc[4][4] = {};   // [fm_d][fn_t] of O^T
  float lpart[4] = {};

  for (int it = 0; it < 16; ++it) {
    const int cur = it & 1;
    __syncthreads();
    if (it + 1 < 16) {
      const int s1 = sBase + (it + 1) * 64;
      #pragma unroll
      for (int c = 0; c < 4; ++c) {
        stage8(kbase + (size_t)s1 * HD, HD, sm.kv[p][0][1 - cur], tw * 32 + c * 8, lane);
        stage8(vbase + s1, TT, sm.kv[p][1][1 - cur], tw * 32 + c * 8, lane);
      }
    }

    // ---- S^T[s][t] = K.Q (scale+log2e folded into Q)
    f32x4 sacc[4][4] = {};
    #pragma unroll
    for (int ks = 0; ks < 2; ++ks) {
      bfrag kf[4];
      #pragma unroll
      for (int fm = 0; fm < 4; ++fm)
        kf[fm] = *fragp(sm.kv[p][0][cur], fm * 16 + l16, ks * 32 + quad * 8);
      #pragma unroll
      for (int fm = 0; fm < 4; ++fm)
        #pragma unroll
        for (int fn = 0; fn < 4; ++fn)
          sacc[fm][fn] = mfma_bf16(kf[fm], qf[fn][ks], sacc[fm][fn]);
    }

    // ---- exp2 in registers; pack 16-s frag pairs into x32 B-operands
    union PB { __bf16 hh[8]; bfrag v; } pb[2][4];
    #pragma unroll
    for (int fm = 0; fm < 4; ++fm)
      #pragma unroll
      for (int fn = 0; fn < 4; ++fn) {
        const float p0 = __builtin_amdgcn_exp2f(sacc[fm][fn][0]);
        const float p1 = __builtin_amdgcn_exp2f(sacc[fm][fn][1]);
        const float p2 = __builtin_amdgcn_exp2f(sacc[fm][fn][2]);
        const float p3 = __builtin_amdgcn_exp2f(sacc[fm][fn][3]);
        lpart[fn] += (p0 + p1) + (p2 + p3);
        const int hb = (fm & 1) * 4;
        pb[fm >> 1][fn].hh[hb + 0] = (__bf16)p0;
        pb[fm >> 1][fn].hh[hb + 1] = (__bf16)p1;
        pb[fm >> 1][fn].hh[hb + 2] = (__bf16)p2;
        pb[fm >> 1][fn].hh[hb + 3] = (__bf16)p3;
      }

    // ---- O^T[d][t] += V^T.P^T
    #pragma unroll
    for (int ks = 0; ks < 2; ++ks) {
      bfrag vf[4];
      #pragma unroll
      for (int fm = 0; fm < 4; ++fm) {
        const __bf16* base = sm.kv[p][1][cur] + (fm * 16 + l16) * 64;
        const int sw = l16 & 7, qh = quad >> 1, qo = (quad & 1) * 4;
        union VF { s16x4 q[2]; bfrag v; } u;
        u.q[0] = *(const s16x4*)(base + (((ks * 4 + qh) ^ sw) << 3) + qo);
        u.q[1] = *(const s16x4*)(base + (((ks * 4 + 2 + qh) ^ sw) << 3) + qo);
        vf[fm] = u.v;
      }
      #pragma unroll
      for (int fm = 0; fm < 4; ++fm)
        #pragma unroll
        for (int fn = 0; fn < 4; ++fn)
          oacc[fm][fn] = mfma_bf16(vf[fm], pb[ks][fn].v, oacc[fm][fn]);
    }
  }

  #pragma unroll
  for (int fn = 0; fn < 4; ++fn) {
    float v = lpart[fn];
    v += __shfl_xor(v, 16);
    v += __shfl_xor(v, 32);
    lpart[fn] = v;
  }
  if (quad == 0)
    #pragma unroll
    for (int fn = 0; fn < 4; ++fn)
      Lsum[p][tw * 64 + fn * 16 + l16] = lpart[fn];

  __syncthreads();

  if (p == 1) {
    #pragma unroll
    for (int fm = 0; fm < 4; ++fm)
      #pragma unroll
      for (int fn = 0; fn < 4; ++fn)
        #pragma unroll
        for (int r = 0; r < 4; ++r)
          sm.om[tw][(fm * 16 + quad * 4 + r) * 64 + fn * 16 + l16] = oacc[fm][fn][r];
  }
  if (tid < 128) {
    const float linv = 1.0f / (Lsum[0][tid] + Lsum[1][tid]);
    LinvS[tid] = linv;
    linv_ws[bh * TT + t0 + tid] = linv;
  }
  __syncthreads();

  if (p == 0) {
    float li[4];
    #pragma unroll
    for (int fn = 0; fn < 4; ++fn) li[fn] = LinvS[tw * 64 + fn * 16 + l16];
    #pragma unroll
    for (int fm = 0; fm < 4; ++fm)
      #pragma unroll
      for (int fn = 0; fn < 4; ++fn) {
        const int t = t0 + tw * 64 + fn * 16 + l16;
        struct alignas(8) B4 { __bf16 a0, a1, a2, a3; };
        B4 o;
        __bf16* op = &o.a0;
        #pragma unroll
        for (int r = 0; r < 4; ++r) {
          const float v = (oacc[fm][fn][r] +
              sm.om[tw][(fm * 16 + quad * 4 + r) * 64 + fn * 16 + l16]) * li[fn];
          op[r] = (__bf16)v;
        }
        *(B4*)(ob + ((size_t)t * BBATCH + b) * EE + h * HD + fm * 16 + quad * 4) = o;
      }
  }
}

// ---------------- avg_w: mean over heads of softmax probs ----------------
// (unchanged from r7: LDS dbuf over h, one barrier per head)
__global__ __launch_bounds__(256, 2) void avg_attn(const __bf16* __restrict__ qb,
                                                   const __bf16* __restrict__ kb,
                                                   const float* __restrict__ linv_ws,
                                                   float* __restrict__ avg_out) {
  __shared__ __bf16 Qs[2][128 * 64];   // 2 x 16KB
  __shared__ __bf16 Ks[2][128 * 64];   // 2 x 16KB

  const int tid = threadIdx.x, lane = tid & 63, w = tid >> 6;
  const int wm = w >> 1, wn = w & 1;
  const int quad = lane >> 4, l16 = lane & 15;

  const int bx = blockIdx.x;
  const int xcd = bx & 7, slot = bx >> 3;
  const int bti = xcd * 4 + (slot >> 4);
  const int s0 = (slot & 15) * 128;
  const int b = bti >> 4, t0 = (bti & 15) * 128;

  const __bf16* qt = qb + (((size_t)b * HN) * TT + t0) * HD;
  const __bf16* kt = kb + (((size_t)b * HN) * TT + s0) * HD;
  const float* lrow0 = linv_ws + ((size_t)b * HN) * TT + t0 + wm * 64;

  #pragma unroll
  for (int c = 0; c < 4; ++c) {
    stage8(qt, HD, Qs[0], w * 32 + c * 8, lane);
    stage8(kt, HD, Ks[0], w * 32 + c * 8, lane);
  }

  f32x4 aacc[4][4] = {};

  for (int h = 0; h < HN; ++h) {
    const int cur = h & 1;
    __syncthreads();
    if (h + 1 < HN) {
      const __bf16* qn = qt + (size_t)(h + 1) * TT * HD;
      const __bf16* kn = kt + (size_t)(h + 1) * TT * HD;
      #pragma unroll
      for (int c = 0; c < 4; ++c) {
        stage8(qn, HD, Qs[1 - cur], w * 32 + c * 8, lane);
        stage8(kn, HD, Ks[1 - cur], w * 32 + c * 8, lane);
      }
    }

    f32x4 sacc[4][4] = {};
    #pragma unroll
    for (int ks = 0; ks < 2; ++ks) {
      bfrag qf4[4], kf4[4];
      #pragma unroll
      for (int f = 0; f < 4; ++f)
        qf4[f] = *fragp(Qs[cur], wm * 64 + f * 16 + l16, ks * 32 + quad * 8);
      #pragma unroll
      for (int f = 0; f < 4; ++f)
        kf4[f] = *fragp(Ks[cur], wn * 64 + f * 16 + l16, ks * 32 + quad * 8);
      #pragma unroll
      for (int fm = 0; fm < 4; ++fm)
        #pragma unroll
        for (int fn = 0; fn < 4; ++fn)
          sacc[fm][fn] = mfma_bf16(qf4[fm], kf4[fn], sacc[fm][fn]);
    }

    const float* lr = lrow0 + (size_t)h * TT;
    f32x4 lvv[4];
    #pragma unroll
    for (int fm = 0; fm < 4; ++fm)
      lvv[fm] = *(const f32x4*)(lr + fm * 16 + quad * 4);

    #pragma unroll
    for (int fm = 0; fm < 4; ++fm)
      #pragma unroll
      for (int fn = 0; fn < 4; ++fn)
        #pragma unroll
        for (int r = 0; r < 4; ++r)
          aacc[fm][fn][r] += __builtin_amdgcn_exp2f(sacc[fm][fn][r]) * lvv[fm][r];
  }

  const float invh = 1.0f / (float)HN;
  #pragma unroll
  for (int fm = 0; fm < 4; ++fm)
    #pragma unroll
    for (int r = 0; r < 4; ++r) {
      const int t = t0 + wm * 64 + fm * 16 + quad * 4 + r;
      #pragma unroll
      for (int fn = 0; fn < 4; ++fn) {
        const int s = s0 + wn * 64 + fn * 16 + l16;
        avg_out[((size_t)b * TT + t) * TT + s] = aacc[fm][fn][r] * invh;
      }
    }
}

extern "C" void kernel_launch(void* const* d_in, const int* in_sizes, int n_in,
                              void* d_out, int out_size, void* d_ws, size_t ws_size,
                              hipStream_t stream) {
  (void)in_sizes; (void)n_in; (void)out_size; (void)ws_size;
  const float* query = (const float*)d_in[0];
  const float* key   = (const float*)d_in[1];
  const float* value = (const float*)d_in[2];
  const float* Wq = (const float*)d_in[3];
  const float* bq = (const float*)d_in[4];
  const float* Wk = (const float*)d_in[5];
  const float* bk = (const float*)d_in[6];
  const float* Wv = (const float*)d_in[7];
  const float* bv = (const float*)d_in[8];
  const float* Wo = (const float*)d_in[9];
  const float* bo = (const float*)d_in[10];

  char* ws = (char*)d_ws;
  size_t off = 0;
  auto wsalloc = [&](size_t bytes) -> void* {
    void* p = ws + off;
    off += (bytes + 255) & ~(size_t)255;
    return p;
  };
  const size_t XE = (size_t)MM * EE;
  const size_t WE = (size_t)EE * EE;
  __bf16* xq   = (__bf16*)wsalloc(XE * 2);
  __bf16* xk   = (__bf16*)wsalloc(XE * 2);
  __bf16* xv   = (__bf16*)wsalloc(XE * 2);
  __bf16* wqb  = (__bf16*)wsalloc(WE * 2);
  __bf16* wkb  = (__bf16*)wsalloc(WE * 2);
  __bf16* wvb  = (__bf16*)wsalloc(WE * 2);
  __bf16* wob  = (__bf16*)wsalloc(WE * 2);
  __bf16* qbuf = (__bf16*)wsalloc(XE * 2);
  __bf16* kbuf = (__bf16*)wsalloc(XE * 2);
  __bf16* vtbuf= (__bf16*)wsalloc(XE * 2);
  __bf16* obuf = (__bf16*)wsalloc(XE * 2);
  float* linv  = (float*)wsalloc((size_t)BBATCH * HN * TT * 4);

  CvtArgs ca;
  ca.src[0] = query; ca.dst[0] = xq;  ca.n4[0] = (int)(XE / 4);
  ca.src[1] = key;   ca.dst[1] = xk;  ca.n4[1] = (int)(XE / 4);
  ca.src[2] = value; ca.dst[2] = xv;  ca.n4[2] = (int)(XE / 4);
  ca.src[3] = Wq;    ca.dst[3] = wqb; ca.n4[3] = (int)(WE / 4);
  ca.src[4] = Wk;    ca.dst[4] = wkb; ca.n4[4] = (int)(WE / 4);
  ca.src[5] = Wv;    ca.dst[5] = wvb; ca.n4[5] = (int)(WE / 4);
  ca.src[6] = Wo;    ca.dst[6] = wob; ca.n4[6] = (int)(WE / 4);
  cvt_all<<<dim3(4096, 1, 7), 256, 0, stream>>>(ca);

  gemm_qkv<<<dim3(768), 256, 0, stream>>>(xq, xk, xv, wqb, wkb, wvb,
                                          bq, bk, bv, qbuf, kbuf, vtbuf);

  attn_fwd<<<dim3(512), 256, 0, stream>>>(qbuf, kbuf, vtbuf, obuf, linv);

  float* avg_out = (float*)d_out + (size_t)TT * BBATCH * EE;
  avg_attn<<<dim3(512), 256, 0, stream>>>(qbuf, kbuf, linv, avg_out);

  gemm_o<<<dim3(512), 256, 0, stream>>>(obuf, wob, bo, (float*)d_out);
}

// Round 9
// 244.795 us; speedup vs baseline: 2.0884x; 1.0107x over previous
//
#include <hip/hip_runtime.h>
#include <hip/hip_bf16.h>
#include <stdint.h>

#define HN 16      // heads
#define TT 2048    // seq len (T == S)
#define BBATCH 2
#define EE 1024
#define HD 64
#define MM 4096    // TT*BBATCH

// Q projection pre-scaled by 0.125*log2(e): exp2(q'.k) == exp(0.125*q.k).
#define SCALEQ 0.18033688011112042f

typedef __attribute__((ext_vector_type(8))) __bf16 bfrag;
typedef __attribute__((ext_vector_type(4))) float f32x4;
typedef __attribute__((ext_vector_type(4))) short s16x4;

__device__ __forceinline__ void gll16(const void* g, void* lds) {
  __builtin_amdgcn_global_load_lds(
      (const __attribute__((address_space(1))) void*)g,
      (__attribute__((address_space(3))) void*)lds, 16, 0, 0);
}

__device__ __forceinline__ f32x4 mfma_bf16(bfrag a, bfrag b, f32x4 c) {
  return __builtin_amdgcn_mfma_f32_16x16x32_bf16(a, b, c, 0, 0, 0);
}

// ---- XOR-swizzled 64-elem-row LDS tiles (16B chunk c of row r at c^(r&7)) --
__device__ __forceinline__ const bfrag* fragp(const __bf16* base, int row, int e) {
  return (const bfrag*)(base + row * 64 + ((((e >> 3) ^ row) & 7) << 3));
}
__device__ __forceinline__ void stage8(const __bf16* grow0, int gstride,
                                       __bf16* tile, int r0, int lane) {
  const int rr = lane >> 3;
  const int cl = (lane & 7) ^ rr;
  gll16(grow0 + (size_t)(r0 + rr) * gstride + cl * 8, tile + r0 * 64);
}

// ---------------- fp32 -> bf16 conversion (7 tensors in one launch) -------
struct CvtArgs {
  const float* src[7];
  __bf16* dst[7];
  int n4[7];
};

__global__ __launch_bounds__(256) void cvt_all(CvtArgs a) {
  const int z = blockIdx.z;
  const int i = blockIdx.x * 256 + threadIdx.x;
  if (i < a.n4[z]) {
    float4 v = ((const float4*)a.src[z])[i];
    struct alignas(8) B4 { __bf16 a0, a1, a2, a3; };
    B4 o = {(__bf16)v.x, (__bf16)v.y, (__bf16)v.z, (__bf16)v.w};
    ((B4*)a.dst[z])[i] = o;
  }
}

// ---------------- GEMM core v2: BK=64, swizzled LDS, dbuf, 1 barrier/iter --
template <int MT>
__device__ __forceinline__ void gemm2(const __bf16* __restrict__ X,
                                      const __bf16* __restrict__ W,
                                      const float* __restrict__ bias,
                                      void* __restrict__ out, int mode,
                                      float scale, int m0, int n0,
                                      __bf16* As0, __bf16* As1,
                                      __bf16* Bs0, __bf16* Bs1) {
  const int tid = threadIdx.x, lane = tid & 63, w = tid >> 6;
  const int wm = w >> 1, wn = w & 1;
  const int quad = lane >> 4, l16 = lane & 15;
  constexpr int FM = MT / 32;   // m-frags per wave

  auto stageAB = [&](int buf, int k0) {
    __bf16* A = buf ? As1 : As0;
    __bf16* B = buf ? Bs1 : Bs0;
    #pragma unroll
    for (int c = 0; c < FM; ++c)
      stage8(X + (size_t)m0 * EE + k0, EE, A, w * (MT / 4) + c * 8, lane);
    #pragma unroll
    for (int c = 0; c < 4; ++c)
      stage8(W + (size_t)n0 * EE + k0, EE, B, w * 32 + c * 8, lane);
  };

  stageAB(0, 0);

  f32x4 acc[FM][4] = {};

  for (int it = 0; it < EE / 64; ++it) {
    const int cur = it & 1;
    __syncthreads();                 // buf[cur] staged; prior reads done
    if (it + 1 < EE / 64) stageAB(1 - cur, (it + 1) * 64);

    const __bf16* A = cur ? As1 : As0;
    const __bf16* B = cur ? Bs1 : Bs0;
    #pragma unroll
    for (int ks = 0; ks < 2; ++ks) {
      bfrag a[FM], b[4];
      #pragma unroll
      for (int f = 0; f < FM; ++f)
        a[f] = *fragp(A, wm * (MT / 2) + f * 16 + l16, ks * 32 + quad * 8);
      #pragma unroll
      for (int f = 0; f < 4; ++f)
        b[f] = *fragp(B, wn * 64 + f * 16 + l16, ks * 32 + quad * 8);
      #pragma unroll
      for (int fm = 0; fm < FM; ++fm)
        #pragma unroll
        for (int fn = 0; fn < 4; ++fn)
          acc[fm][fn] = mfma_bf16(a[fm], b[fn], acc[fm][fn]);
    }
  }

  float bv[4];
  #pragma unroll
  for (int fn = 0; fn < 4; ++fn) bv[fn] = bias[n0 + wn * 64 + fn * 16 + l16];

  #pragma unroll
  for (int fm = 0; fm < FM; ++fm) {
    #pragma unroll
    for (int r = 0; r < 4; ++r) {
      const int gm = m0 + wm * (MT / 2) + fm * 16 + quad * 4 + r;
      #pragma unroll
      for (int fn = 0; fn < 4; ++fn) {
        const int gn = n0 + wn * 64 + fn * 16 + l16;
        const float v = (acc[fm][fn][r] + bv[fn]) * scale;
        if (mode == 0) {
          const int t = gm >> 1, bb = gm & 1, h = gn >> 6, d = gn & 63;
          ((__bf16*)out)[(((size_t)(bb * HN + h)) * TT + t) * HD + d] = (__bf16)v;
        } else if (mode == 2) {
          const int s = gm >> 1, bb = gm & 1, h = gn >> 6, d = gn & 63;
          ((__bf16*)out)[(((size_t)(bb * HN + h)) * HD + d) * TT + s] = (__bf16)v;
        } else {
          ((float*)out)[(size_t)gm * EE + gn] = v;
        }
      }
    }
  }
}

// flat grid 768: bx = m + 32*(n + 8*z). bx%8 == m%8 -> the 8 n-blocks
// sharing one A-tile land on one XCD (A-tiles 1MB + B 2MB fit 4MB L2).
__global__ __launch_bounds__(256, 2) void gemm_qkv(
    const __bf16* __restrict__ xq, const __bf16* __restrict__ xk,
    const __bf16* __restrict__ xv, const __bf16* __restrict__ wq,
    const __bf16* __restrict__ wk, const __bf16* __restrict__ wv,
    const float* __restrict__ bq, const float* __restrict__ bk,
    const float* __restrict__ bv, __bf16* __restrict__ qo,
    __bf16* __restrict__ ko, __bf16* __restrict__ vo) {
  __shared__ __bf16 As[2][128 * 64];   // 32KB
  __shared__ __bf16 Bs[2][128 * 64];   // 32KB
  const int bx = blockIdx.x;
  const int m = bx & 31, n = (bx >> 5) & 7, z = bx >> 8;
  const __bf16 *X, *W;
  const float* bias;
  __bf16* out;
  int mode;
  float scale;
  if (z == 0)      { X = xq; W = wq; bias = bq; out = qo; mode = 0; scale = SCALEQ; }
  else if (z == 1) { X = xk; W = wk; bias = bk; out = ko; mode = 0; scale = 1.0f; }
  else             { X = xv; W = wv; bias = bv; out = vo; mode = 2; scale = 1.0f; }
  gemm2<128>(X, W, bias, out, mode, scale, m * 128, n * 128,
             As[0], As[1], Bs[0], Bs[1]);
}

// output GEMM: MT=64, flat grid 512: bx = m + 64*n (bx%8 == m%8).
__global__ __launch_bounds__(256, 2) void gemm_o(const __bf16* __restrict__ X,
                                                 const __bf16* __restrict__ W,
                                                 const float* __restrict__ bias,
                                                 float* __restrict__ out) {
  __shared__ __bf16 As[2][64 * 64];    // 16KB
  __shared__ __bf16 Bs[2][128 * 64];   // 32KB
  const int bx = blockIdx.x;
  const int m = bx & 63, n = bx >> 6;
  gemm2<64>(X, W, bias, out, 3, 1.0f, m * 64, n * 128,
            As[0], As[1], Bs[0], Bs[1]);
}

// ---------------- flash attention fwd: O (normalized) + linv -------------
// r8 + ones-MFMA row-sums: l[t] = P.1 computed on the matrix pipe
// (8 extra MFMA/iter) instead of 64 VALU adds/iter + end shuffles.
__global__ __launch_bounds__(256, 2) void attn_fwd(const __bf16* __restrict__ qb,
                                                   const __bf16* __restrict__ kb,
                                                   const __bf16* __restrict__ vtb,
                                                   __bf16* __restrict__ ob,
                                                   float* __restrict__ linv_ws) {
  union Sh {
    __bf16 kv[2][2][2][64 * 64];  // [pair][K=0/V=1][buf] 64KB
    float om[2][64 * 64];         // epilogue O-merge scratch (32KB, aliased)
  };
  __shared__ Sh sm;
  __shared__ float Lsum[2][128];
  __shared__ float LinvS[128];

  const int tid = threadIdx.x, lane = tid & 63, w = tid >> 6;
  const int p = w >> 1, tw = w & 1;
  const int quad = lane >> 4, l16 = lane & 15;

  const int bx = blockIdx.x;
  const int xcd = bx & 7, slot = bx >> 3;
  const int bhi = xcd * 4 + (slot >> 4);
  const int t0 = (slot & 15) * 128;
  const int b = bhi >> 4, h = bhi & 15;
  const size_t bh = (size_t)(b * HN + h);

  const __bf16* qbase = qb + (bh * TT + t0) * HD;
  const __bf16* kbase = kb + bh * TT * HD;
  const __bf16* vbase = vtb + bh * HD * TT;
  const int sBase = p * 1024;

  #pragma unroll
  for (int c = 0; c < 4; ++c) {
    stage8(kbase + (size_t)sBase * HD, HD, sm.kv[p][0][0], tw * 32 + c * 8, lane);
    stage8(vbase + sBase, TT, sm.kv[p][1][0], tw * 32 + c * 8, lane);
  }

  bfrag qf[4][2];
  #pragma unroll
  for (int fn = 0; fn < 4; ++fn)
    #pragma unroll
    for (int ks = 0; ks < 2; ++ks)
      qf[fn][ks] = *(const bfrag*)(qbase +
          (size_t)(tw * 64 + fn * 16 + l16) * HD + ks * 32 + quad * 8);

  bfrag ones;
  {
    union { short s[8]; bfrag v; } u;
    #pragma unroll
    for (int i = 0; i < 8; ++i) u.s[i] = 0x3F80;   // bf16 1.0
    ones = u.v;
  }

  f32x4 oacc[4][4] = {};   // [fm_d][fn_t] of O^T
  f32x4 lacc[4] = {};      // row sums via ones-MFMA (all r identical)

  for (int it = 0; it < 16; ++it) {
    const int cur = it & 1;
    __syncthreads();
    if (it + 1 < 16) {
      const int s1 = sBase + (it + 1) * 64;
      #pragma unroll
      for (int c = 0; c < 4; ++c) {
        stage8(kbase + (size_t)s1 * HD, HD, sm.kv[p][0][1 - cur], tw * 32 + c * 8, lane);
        stage8(vbase + s1, TT, sm.kv[p][1][1 - cur], tw * 32 + c * 8, lane);
      }
    }

    // ---- S^T[s][t] = K.Q (scale+log2e folded into Q)
    f32x4 sacc[4][4] = {};
    #pragma unroll
    for (int ks = 0; ks < 2; ++ks) {
      bfrag kf[4];
      #pragma unroll
      for (int fm = 0; fm < 4; ++fm)
        kf[fm] = *fragp(sm.kv[p][0][cur], fm * 16 + l16, ks * 32 + quad * 8);
      #pragma unroll
      for (int fm = 0; fm < 4; ++fm)
        #pragma unroll
        for (int fn = 0; fn < 4; ++fn)
          sacc[fm][fn] = mfma_bf16(kf[fm], qf[fn][ks], sacc[fm][fn]);
    }

    // ---- exp2 in registers; pack 16-s frag pairs into x32 B-operands
    union PB { __bf16 hh[8]; bfrag v; } pb[2][4];
    #pragma unroll
    for (int fm = 0; fm < 4; ++fm)
      #pragma unroll
      for (int fn = 0; fn < 4; ++fn) {
        const float p0 = __builtin_amdgcn_exp2f(sacc[fm][fn][0]);
        const float p1 = __builtin_amdgcn_exp2f(sacc[fm][fn][1]);
        const float p2 = __builtin_amdgcn_exp2f(sacc[fm][fn][2]);
        const float p3 = __builtin_amdgcn_exp2f(sacc[fm][fn][3]);
        const int hb = (fm & 1) * 4;
        pb[fm >> 1][fn].hh[hb + 0] = (__bf16)p0;
        pb[fm >> 1][fn].hh[hb + 1] = (__bf16)p1;
        pb[fm >> 1][fn].hh[hb + 2] = (__bf16)p2;
        pb[fm >> 1][fn].hh[hb + 3] = (__bf16)p3;
      }

    // ---- O^T[d][t] += V^T.P^T ; row sums l[t] += 1.P^T on the MFMA pipe
    #pragma unroll
    for (int ks = 0; ks < 2; ++ks) {
      bfrag vf[4];
      #pragma unroll
      for (int fm = 0; fm < 4; ++fm) {
        const __bf16* base = sm.kv[p][1][cur] + (fm * 16 + l16) * 64;
        const int sw = l16 & 7, qh = quad >> 1, qo = (quad & 1) * 4;
        union VF { s16x4 q[2]; bfrag v; } u;
        u.q[0] = *(const s16x4*)(base + (((ks * 4 + qh) ^ sw) << 3) + qo);
        u.q[1] = *(const s16x4*)(base + (((ks * 4 + 2 + qh) ^ sw) << 3) + qo);
        vf[fm] = u.v;
      }
      #pragma unroll
      for (int fn = 0; fn < 4; ++fn)
        lacc[fn] = mfma_bf16(ones, pb[ks][fn].v, lacc[fn]);
      #pragma unroll
      for (int fm = 0; fm < 4; ++fm)
        #pragma unroll
        for (int fn = 0; fn < 4; ++fn)
          oacc[fm][fn] = mfma_bf16(vf[fm], pb[ks][fn].v, oacc[fm][fn]);
    }
  }

  // ---- lacc[fn][r] holds l for t = fn*16+l16 (identical across r, quads)
  if (quad == 0)
    #pragma unroll
    for (int fn = 0; fn < 4; ++fn)
      Lsum[p][tw * 64 + fn * 16 + l16] = lacc[fn][0];

  __syncthreads();   // Lsum visible; all K/V reads done -> om may alias

  if (p == 1) {
    #pragma unroll
    for (int fm = 0; fm < 4; ++fm)
      #pragma unroll
      for (int fn = 0; fn < 4; ++fn)
        #pragma unroll
        for (int r = 0; r < 4; ++r)
          sm.om[tw][(fm * 16 + quad * 4 + r) * 64 + fn * 16 + l16] = oacc[fm][fn][r];
  }
  if (tid < 128) {
    const float linv = 1.0f / (Lsum[0][tid] + Lsum[1][tid]);
    LinvS[tid] = linv;
    linv_ws[bh * TT + t0 + tid] = linv;
  }
  __syncthreads();

  if (p == 0) {
    float li[4];
    #pragma unroll
    for (int fn = 0; fn < 4; ++fn) li[fn] = LinvS[tw * 64 + fn * 16 + l16];
    #pragma unroll
    for (int fm = 0; fm < 4; ++fm)
      #pragma unroll
      for (int fn = 0; fn < 4; ++fn) {
        const int t = t0 + tw * 64 + fn * 16 + l16;
        struct alignas(8) B4 { __bf16 a0, a1, a2, a3; };
        B4 o;
        __bf16* op = &o.a0;
        #pragma unroll
        for (int r = 0; r < 4; ++r) {
          const float v = (oacc[fm][fn][r] +
              sm.om[tw][(fm * 16 + quad * 4 + r) * 64 + fn * 16 + l16]) * li[fn];
          op[r] = (__bf16)v;
        }
        *(B4*)(ob + ((size_t)t * BBATCH + b) * EE + h * HD + fm * 16 + quad * 4) = o;
      }
  }
}

// ---------------- avg_w: mean over heads of softmax probs ----------------
// (unchanged from r8: LDS dbuf over h, one barrier per head)
__global__ __launch_bounds__(256, 2) void avg_attn(const __bf16* __restrict__ qb,
                                                   const __bf16* __restrict__ kb,
                                                   const float* __restrict__ linv_ws,
                                                   float* __restrict__ avg_out) {
  __shared__ __bf16 Qs[2][128 * 64];   // 2 x 16KB
  __shared__ __bf16 Ks[2][128 * 64];   // 2 x 16KB

  const int tid = threadIdx.x, lane = tid & 63, w = tid >> 6;
  const int wm = w >> 1, wn = w & 1;
  const int quad = lane >> 4, l16 = lane & 15;

  const int bx = blockIdx.x;
  const int xcd = bx & 7, slot = bx >> 3;
  const int bti = xcd * 4 + (slot >> 4);
  const int s0 = (slot & 15) * 128;
  const int b = bti >> 4, t0 = (bti & 15) * 128;

  const __bf16* qt = qb + (((size_t)b * HN) * TT + t0) * HD;
  const __bf16* kt = kb + (((size_t)b * HN) * TT + s0) * HD;
  const float* lrow0 = linv_ws + ((size_t)b * HN) * TT + t0 + wm * 64;

  #pragma unroll
  for (int c = 0; c < 4; ++c) {
    stage8(qt, HD, Qs[0], w * 32 + c * 8, lane);
    stage8(kt, HD, Ks[0], w * 32 + c * 8, lane);
  }

  f32x4 aacc[4][4] = {};

  for (int h = 0; h < HN; ++h) {
    const int cur = h & 1;
    __syncthreads();
    if (h + 1 < HN) {
      const __bf16* qn = qt + (size_t)(h + 1) * TT * HD;
      const __bf16* kn = kt + (size_t)(h + 1) * TT * HD;
      #pragma unroll
      for (int c = 0; c < 4; ++c) {
        stage8(qn, HD, Qs[1 - cur], w * 32 + c * 8, lane);
        stage8(kn, HD, Ks[1 - cur], w * 32 + c * 8, lane);
      }
    }

    f32x4 sacc[4][4] = {};
    #pragma unroll
    for (int ks = 0; ks < 2; ++ks) {
      bfrag qf4[4], kf4[4];
      #pragma unroll
      for (int f = 0; f < 4; ++f)
        qf4[f] = *fragp(Qs[cur], wm * 64 + f * 16 + l16, ks * 32 + quad * 8);
      #pragma unroll
      for (int f = 0; f < 4; ++f)
        kf4[f] = *fragp(Ks[cur], wn * 64 + f * 16 + l16, ks * 32 + quad * 8);
      #pragma unroll
      for (int fm = 0; fm < 4; ++fm)
        #pragma unroll
        for (int fn = 0; fn < 4; ++fn)
          sacc[fm][fn] = mfma_bf16(qf4[fm], kf4[fn], sacc[fm][fn]);
    }

    const float* lr = lrow0 + (size_t)h * TT;
    f32x4 lvv[4];
    #pragma unroll
    for (int fm = 0; fm < 4; ++fm)
      lvv[fm] = *(const f32x4*)(lr + fm * 16 + quad * 4);

    #pragma unroll
    for (int fm = 0; fm < 4; ++fm)
      #pragma unroll
      for (int fn = 0; fn < 4; ++fn)
        #pragma unroll
        for (int r = 0; r < 4; ++r)
          aacc[fm][fn][r] += __builtin_amdgcn_exp2f(sacc[fm][fn][r]) * lvv[fm][r];
  }

  const float invh = 1.0f / (float)HN;
  #pragma unroll
  for (int fm = 0; fm < 4; ++fm)
    #pragma unroll
    for (int r = 0; r < 4; ++r) {
      const int t = t0 + wm * 64 + fm * 16 + quad * 4 + r;
      #pragma unroll
      for (int fn = 0; fn < 4; ++fn) {
        const int s = s0 + wn * 64 + fn * 16 + l16;
        avg_out[((size_t)b * TT + t) * TT + s] = aacc[fm][fn][r] * invh;
      }
    }
}

extern "C" void kernel_launch(void* const* d_in, const int* in_sizes, int n_in,
                              void* d_out, int out_size, void* d_ws, size_t ws_size,
                              hipStream_t stream) {
  (void)in_sizes; (void)n_in; (void)out_size; (void)ws_size;
  const float* query = (const float*)d_in[0];
  const float* key   = (const float*)d_in[1];
  const float* value = (const float*)d_in[2];
  const float* Wq = (const float*)d_in[3];
  const float* bq = (const float*)d_in[4];
  const float* Wk = (const float*)d_in[5];
  const float* bk = (const float*)d_in[6];
  const float* Wv = (const float*)d_in[7];
  const float* bv = (const float*)d_in[8];
  const float* Wo = (const float*)d_in[9];
  const float* bo = (const float*)d_in[10];

  char* ws = (char*)d_ws;
  size_t off = 0;
  auto wsalloc = [&](size_t bytes) -> void* {
    void* p = ws + off;
    off += (bytes + 255) & ~(size_t)255;
    return p;
  };
  const size_t XE = (size_t)MM * EE;
  const size_t WE = (size_t)EE * EE;
  __bf16* xq   = (__bf16*)wsalloc(XE * 2);
  __bf16* xk   = (__bf16*)wsalloc(XE * 2);
  __bf16* xv   = (__bf16*)wsalloc(XE * 2);
  __bf16* wqb  = (__bf16*)wsalloc(WE * 2);
  __bf16* wkb  = (__bf16*)wsalloc(WE * 2);
  __bf16* wvb  = (__bf16*)wsalloc(WE * 2);
  __bf16* wob  = (__bf16*)wsalloc(WE * 2);
  __bf16* qbuf = (__bf16*)wsalloc(XE * 2);
  __bf16* kbuf = (__bf16*)wsalloc(XE * 2);
  __bf16* vtbuf= (__bf16*)wsalloc(XE * 2);
  __bf16* obuf = (__bf16*)wsalloc(XE * 2);
  float* linv  = (float*)wsalloc((size_t)BBATCH * HN * TT * 4);

  CvtArgs ca;
  ca.src[0] = query; ca.dst[0] = xq;  ca.n4[0] = (int)(XE / 4);
  ca.src[1] = key;   ca.dst[1] = xk;  ca.n4[1] = (int)(XE / 4);
  ca.src[2] = value; ca.dst[2] = xv;  ca.n4[2] = (int)(XE / 4);
  ca.src[3] = Wq;    ca.dst[3] = wqb; ca.n4[3] = (int)(WE / 4);
  ca.src[4] = Wk;    ca.dst[4] = wkb; ca.n4[4] = (int)(WE / 4);
  ca.src[5] = Wv;    ca.dst[5] = wvb; ca.n4[5] = (int)(WE / 4);
  ca.src[6] = Wo;    ca.dst[6] = wob; ca.n4[6] = (int)(WE / 4);
  cvt_all<<<dim3(4096, 1, 7), 256, 0, stream>>>(ca);

  gemm_qkv<<<dim3(768), 256, 0, stream>>>(xq, xk, xv, wqb, wkb, wvb,
                                          bq, bk, bv, qbuf, kbuf, vtbuf);

  attn_fwd<<<dim3(512), 256, 0, stream>>>(qbuf, kbuf, vtbuf, obuf, linv);

  float* avg_out = (float*)d_out + (size_t)TT * BBATCH * EE;
  avg_attn<<<dim3(512), 256, 0, stream>>>(qbuf, kbuf, linv, avg_out);

  gemm_o<<<dim3(512), 256, 0, stream>>>(obuf, wob, bo, (float*)d_out);
}